// Round 1
// baseline (156.260 us; speedup 1.0000x reference)
//
#include <hip/hip_runtime.h>

#define NSEQ   24
#define NBOX   196
#define NCTX   196
#define MAXLEN 6
#define EPSV   1e-6f

#define TILES      7     // i-tiles per batch
#define IPT        28    // i per tile (7*28 = 196)
#define K1_THREADS 512
#define K1_WAVES   8

// ---------------------------------------------------------------- copy ea
__global__ void copy_kernel(const float* __restrict__ src, float* __restrict__ dst, int n) {
    int i = blockIdx.x * blockDim.x + threadIdx.x;
    if (i < n) dst[i] = src[i];
}

// ------------------------------------------------- per-step: compute add_raw
// add_raw[b,i] = kcls_i * sum_j sum_c cae[j][ctx[b,i,c]] * spo[b,e_j,i,c] * rm[b,i,c]
__global__ __launch_bounds__(K1_THREADS) void step_compute(
    const float* __restrict__ ea,       // [bs, NSEQ, NBOX]  (current state, d_out)
    const float* __restrict__ spo,      // [bs, NSEQ, NBOX, NCTX]
    const int*   __restrict__ ctx,      // [bs, NBOX, NCTX]
    const int*   __restrict__ roi_cls,  // [bs, NBOX]
    const float* __restrict__ rm,       // [bs, NBOX, NCTX]
    const int*   __restrict__ trav,     // [bs, MAXLEN]
    const int*   __restrict__ adj,      // [bs, NSEQ, NSEQ]
    float*       __restrict__ add_raw,  // ws: [bs, NBOX]
    int step)
{
    const int b    = blockIdx.x / TILES;
    const int tile = blockIdx.x % TILES;
    const int tid  = threadIdx.x;

    __shared__ float cae[NSEQ][NBOX];   // ea[b,j,:] * kcls  for each child, compacted
    __shared__ int   s_childE[NSEQ];
    __shared__ int   s_childJ[NSEQ];
    __shared__ int   s_nch;

    const int p = trav[b * MAXLEN + step];
    if (tid == 0) {
        int n = 0;
        if (p >= 0) {
            const int* arow = adj + ((size_t)b * NSEQ + p) * NSEQ;
            for (int j = 0; j < NSEQ; ++j) {
                int e = arow[j];
                if (e >= 0) { s_childJ[n] = j; s_childE[n] = e; ++n; }
            }
        }
        s_nch = n;
    }
    __syncthreads();
    const int nch = s_nch;
    if (nch == 0) return;  // finalize kernel also skips this batch

    // stage child attention rows * kcls into LDS
    for (int t = tid; t < nch * NBOX; t += K1_THREADS) {
        int n = t / NBOX;
        int k = t - n * NBOX;
        float kc = (roi_cls[b * NBOX + k] != -1) ? 1.0f : 0.0f;
        cae[n][k] = ea[((size_t)b * NSEQ + s_childJ[n]) * NBOX + k] * kc;
    }
    __syncthreads();

    const int  wave = tid >> 6;
    const int  lane = tid & 63;
    const bool act  = lane < 49;    // 49 lanes * float4 = 196 = NCTX exactly

    for (int ii = wave; ii < IPT; ii += K1_WAVES) {
        const int i = tile * IPT + ii;
        float acc = 0.0f;
        if (act) {
            const int4   idx4 = ((const int4*)  (ctx + ((size_t)b * NBOX + i) * NCTX))[lane];
            const float4 m4   = ((const float4*)(rm  + ((size_t)b * NBOX + i) * NCTX))[lane];
            float4 a4 = make_float4(0.f, 0.f, 0.f, 0.f);
            for (int n = 0; n < nch; ++n) {
                const float4 s4 = ((const float4*)(spo +
                    (((size_t)b * NSEQ + s_childE[n]) * NBOX + i) * NCTX))[lane];
                a4.x = fmaf(m4.x * cae[n][idx4.x], s4.x, a4.x);
                a4.y = fmaf(m4.y * cae[n][idx4.y], s4.y, a4.y);
                a4.z = fmaf(m4.z * cae[n][idx4.z], s4.z, a4.z);
                a4.w = fmaf(m4.w * cae[n][idx4.w], s4.w, a4.w);
            }
            acc = (a4.x + a4.y) + (a4.z + a4.w);
        }
        #pragma unroll
        for (int off = 32; off >= 1; off >>= 1)
            acc += __shfl_down(acc, off, 64);
        if (lane == 0) {
            float kci = (roi_cls[b * NBOX + i] != -1) ? 1.0f : 0.0f;
            add_raw[b * NBOX + i] = kci * acc;
        }
    }
}

// ------------------------------------------------- per-step: finalize + write
__global__ __launch_bounds__(256) void step_finalize(
    float*       __restrict__ ea,       // [bs, NSEQ, NBOX] in/out
    const float* __restrict__ add_raw,  // ws: [bs, NBOX]
    const float* __restrict__ wc,       // [bs, NSEQ, NBOX]
    const int*   __restrict__ roi_cls,  // [bs, NBOX]
    const int*   __restrict__ trav,     // [bs, MAXLEN]
    const int*   __restrict__ adj,      // [bs, NSEQ, NSEQ]
    int step)
{
    const int b   = blockIdx.x;
    const int tid = threadIdx.x;
    const int p   = trav[b * MAXLEN + step];

    int nch = 0;
    if (p >= 0) {
        const int* arow = adj + ((size_t)b * NSEQ + p) * NSEQ;
        for (int j = 0; j < NSEQ; ++j) nch += (arow[j] >= 0) ? 1 : 0;
    }
    if (p < 0 || nch == 0) return;  // row stays unchanged

    float upd = 0.0f, a = 0.0f;
    if (tid < NBOX) {
        const float sub = ea[((size_t)b * NSEQ + p) * NBOX + tid];
        const float w   = wc[((size_t)b * NSEQ + p) * NBOX + tid];
        upd = sub + (add_raw[b * NBOX + tid] + (float)nch * EPSV) * w;
        a = fabsf(upd);
    }
    #pragma unroll
    for (int off = 32; off >= 1; off >>= 1)
        a = fmaxf(a, __shfl_down(a, off, 64));
    __shared__ float wmax[4];
    if ((tid & 63) == 0) wmax[tid >> 6] = a;
    __syncthreads();
    float norm = fmaxf(fmaxf(wmax[0], wmax[1]), fmaxf(wmax[2], wmax[3]));
    norm = (norm <= 1.0f) ? 1.0f : norm;
    if (tid < NBOX) {
        float val = upd / norm;
        if (roi_cls[b * NBOX + tid] == -1) val = -1.0f;
        ea[((size_t)b * NSEQ + p) * NBOX + tid] = val;
    }
}

extern "C" void kernel_launch(void* const* d_in, const int* in_sizes, int n_in,
                              void* d_out, int out_size, void* d_ws, size_t ws_size,
                              hipStream_t stream) {
    const int*   trav = (const int*)  d_in[0];
    const int*   adj  = (const int*)  d_in[1];
    const float* ent  = (const float*)d_in[2];
    const float* spo  = (const float*)d_in[3];
    const int*   ctx  = (const int*)  d_in[4];
    const int*   roi  = (const int*)  d_in[5];
    const float* rm   = (const float*)d_in[6];
    const float* wc   = (const float*)d_in[7];

    float* ea      = (float*)d_out;
    float* add_raw = (float*)d_ws;   // bs*NBOX floats (~25 KB)

    const int bs = in_sizes[0] / MAXLEN;
    const int n  = bs * NSEQ * NBOX;

    copy_kernel<<<(n + 255) / 256, 256, 0, stream>>>(ent, ea, n);

    for (int t = 0; t < MAXLEN; ++t) {
        step_compute<<<bs * TILES, K1_THREADS, 0, stream>>>(
            ea, spo, ctx, roi, rm, trav, adj, add_raw, t);
        step_finalize<<<bs, 256, 0, stream>>>(
            ea, add_raw, wc, roi, trav, adj, t);
    }
}

// Round 2
// 105.143 us; speedup vs baseline: 1.4862x; 1.4862x over previous
//
#include <hip/hip_runtime.h>

#define NSEQ   24
#define NBOX   196
#define NCTX   196
#define MAXLEN 6
#define EPSV   1e-6f

#define TILES      25    // i-tiles per batch: tile covers K1_WAVES i's
#define K1_THREADS 512
#define K1_WAVES   8     // 25*8 = 200 >= 196

// ------------------------------------------------- per-step: compute add_raw
// add_raw[b,i] = kcls_i * sum_j sum_c cae[j][ctx[b,i,c]] * spo[b,e_j,i,c] * rm[b,i,c]
__global__ __launch_bounds__(K1_THREADS) void step_compute(
    const float* __restrict__ src,      // ent (step 0) or ea (current state)
    float*       __restrict__ ea_copy,  // ea; written only when do_copy
    const float* __restrict__ spo,      // [bs, NSEQ, NBOX, NCTX]
    const int*   __restrict__ ctx,      // [bs, NBOX, NCTX]
    const int*   __restrict__ roi_cls,  // [bs, NBOX]
    const float* __restrict__ rm,       // [bs, NBOX, NCTX]
    const int*   __restrict__ trav,     // [bs, MAXLEN]
    const int*   __restrict__ adj,      // [bs, NSEQ, NSEQ]
    float*       __restrict__ add_raw,  // ws: [bs, NBOX]
    int step, int do_copy)
{
    const int b    = blockIdx.x / TILES;
    const int tile = blockIdx.x % TILES;
    const int tid  = threadIdx.x;

    __shared__ __align__(16) float cae[NSEQ][NBOX]; // child rows * kcls, compacted
    __shared__ int   s_childE[NSEQ + 1];            // +1 pad for prefetch
    __shared__ int   s_childJ[NSEQ];
    __shared__ int   s_nch;

    // fused ent -> ea copy on step 0 (no kernel in this dispatch reads ea)
    if (do_copy) {
        const int total4 = 32 * NSEQ * NBOX / 4;  // bs*nseq*nbox/4 (bs=32)
        int idx = blockIdx.x * K1_THREADS + tid;
        if (idx < total4)
            ((float4*)ea_copy)[idx] = ((const float4*)src)[idx];
    }

    const int p = trav[b * MAXLEN + step];
    if (tid == 0) {
        int n = 0;
        if (p >= 0) {
            const int* arow = adj + ((size_t)b * NSEQ + p) * NSEQ;
            for (int j = 0; j < NSEQ; ++j) {
                int e = arow[j];
                if (e >= 0) { s_childJ[n] = j; s_childE[n] = e; ++n; }
            }
        }
        if (n > 0) s_childE[n] = s_childE[0];  // pad so prefetch load is safe
        s_nch = n;
    }
    __syncthreads();
    const int nch = s_nch;
    if (nch == 0) return;  // finalize kernel also skips this batch

    // stage child attention rows * kcls into LDS (float4)
    {
        const int items = nch * (NBOX / 4);   // 49 float4 per child
        const int4* roi4 = (const int4*)(roi_cls + b * NBOX);
        for (int t = tid; t < items; t += K1_THREADS) {
            int n = t / (NBOX / 4);
            int q = t - n * (NBOX / 4);
            float4 e4 = ((const float4*)(src + ((size_t)b * NSEQ + s_childJ[n]) * NBOX))[q];
            int4   r4 = roi4[q];
            float4 v;
            v.x = (r4.x != -1) ? e4.x : 0.0f;
            v.y = (r4.y != -1) ? e4.y : 0.0f;
            v.z = (r4.z != -1) ? e4.z : 0.0f;
            v.w = (r4.w != -1) ? e4.w : 0.0f;
            ((float4*)&cae[n][0])[q] = v;
        }
    }
    __syncthreads();

    const int  wave = tid >> 6;
    const int  lane = tid & 63;
    const int  i    = tile * K1_WAVES + wave;   // one i per wave
    if (i >= NBOX) return;

    float acc = 0.0f;
    const bool act = lane < 49;                 // 49 lanes * float4 = 196 = NCTX
    if (act) {
        const size_t bi = (size_t)b * NBOX + i;
        const int4   idx4 = ((const int4*)  (ctx + bi * NCTX))[lane];
        const float4 m4   = ((const float4*)(rm  + bi * NCTX))[lane];
        const float* sbase = spo + ((size_t)b * NSEQ * NBOX + i) * NCTX;

        float4 a4 = make_float4(0.f, 0.f, 0.f, 0.f);
        float4 s4 = ((const float4*)(sbase + (size_t)s_childE[0] * NBOX * NCTX))[lane];
        for (int n = 0; n < nch; ++n) {
            // unconditional prefetch of n+1 (padded child list -> valid address)
            float4 nx = ((const float4*)(sbase + (size_t)s_childE[n + 1] * NBOX * NCTX))[lane];
            a4.x = fmaf(m4.x * cae[n][idx4.x], s4.x, a4.x);
            a4.y = fmaf(m4.y * cae[n][idx4.y], s4.y, a4.y);
            a4.z = fmaf(m4.z * cae[n][idx4.z], s4.z, a4.z);
            a4.w = fmaf(m4.w * cae[n][idx4.w], s4.w, a4.w);
            s4 = nx;
        }
        acc = (a4.x + a4.y) + (a4.z + a4.w);
    }
    #pragma unroll
    for (int off = 32; off >= 1; off >>= 1)
        acc += __shfl_down(acc, off, 64);
    if (lane == 0) {
        float kci = (roi_cls[b * NBOX + i] != -1) ? 1.0f : 0.0f;
        add_raw[b * NBOX + i] = kci * acc;
    }
}

// ------------------------------------------------- per-step: finalize + write
__global__ __launch_bounds__(256) void step_finalize(
    float*       __restrict__ ea,       // [bs, NSEQ, NBOX] in/out
    const float* __restrict__ add_raw,  // ws: [bs, NBOX]
    const float* __restrict__ wc,       // [bs, NSEQ, NBOX]
    const int*   __restrict__ roi_cls,  // [bs, NBOX]
    const int*   __restrict__ trav,     // [bs, MAXLEN]
    const int*   __restrict__ adj,      // [bs, NSEQ, NSEQ]
    int step)
{
    const int b   = blockIdx.x;
    const int tid = threadIdx.x;
    const int p   = trav[b * MAXLEN + step];

    int nch = 0;
    if (p >= 0) {
        const int* arow = adj + ((size_t)b * NSEQ + p) * NSEQ;
        for (int j = 0; j < NSEQ; ++j) nch += (arow[j] >= 0) ? 1 : 0;
    }
    if (p < 0 || nch == 0) return;  // row stays unchanged

    float upd = 0.0f, a = 0.0f;
    if (tid < NBOX) {
        const float sub = ea[((size_t)b * NSEQ + p) * NBOX + tid];
        const float w   = wc[((size_t)b * NSEQ + p) * NBOX + tid];
        upd = sub + (add_raw[b * NBOX + tid] + (float)nch * EPSV) * w;
        a = fabsf(upd);
    }
    #pragma unroll
    for (int off = 32; off >= 1; off >>= 1)
        a = fmaxf(a, __shfl_down(a, off, 64));
    __shared__ float wmax[4];
    if ((tid & 63) == 0) wmax[tid >> 6] = a;
    __syncthreads();
    float norm = fmaxf(fmaxf(wmax[0], wmax[1]), fmaxf(wmax[2], wmax[3]));
    norm = (norm <= 1.0f) ? 1.0f : norm;
    if (tid < NBOX) {
        float val = upd / norm;
        if (roi_cls[b * NBOX + tid] == -1) val = -1.0f;
        ea[((size_t)b * NSEQ + p) * NBOX + tid] = val;
    }
}

extern "C" void kernel_launch(void* const* d_in, const int* in_sizes, int n_in,
                              void* d_out, int out_size, void* d_ws, size_t ws_size,
                              hipStream_t stream) {
    const int*   trav = (const int*)  d_in[0];
    const int*   adj  = (const int*)  d_in[1];
    const float* ent  = (const float*)d_in[2];
    const float* spo  = (const float*)d_in[3];
    const int*   ctx  = (const int*)  d_in[4];
    const int*   roi  = (const int*)  d_in[5];
    const float* rm   = (const float*)d_in[6];
    const float* wc   = (const float*)d_in[7];

    float* ea      = (float*)d_out;
    float* add_raw = (float*)d_ws;   // bs*NBOX floats (~25 KB)

    const int bs = in_sizes[0] / MAXLEN;

    for (int t = 0; t < MAXLEN; ++t) {
        step_compute<<<bs * TILES, K1_THREADS, 0, stream>>>(
            t == 0 ? ent : ea, ea, spo, ctx, roi, rm, trav, adj, add_raw,
            t, t == 0 ? 1 : 0);
        step_finalize<<<bs, 256, 0, stream>>>(
            ea, add_raw, wc, roi, trav, adj, t);
    }
}